// Round 17
// baseline (120.298 us; speedup 1.0000x reference)
//
#include <hip/hip_runtime.h>
#include <stdint.h>

#define DEVINL __device__ __forceinline__

typedef short s16x8 __attribute__((ext_vector_type(8)));
typedef short s16x4 __attribute__((ext_vector_type(4)));
typedef float f32x4 __attribute__((ext_vector_type(4)));
typedef int   i32x4 __attribute__((ext_vector_type(4)));

DEVINL f32x4 MFMA16(s16x8 a, s16x8 b, f32x4 c) {
  return __builtin_amdgcn_mfma_f32_16x16x32_bf16(a, b, c, 0, 0, 0);
}

DEVINL short f2bf(float f) {
  uint32_t u = __float_as_uint(f);
  uint32_t r = (u + 0x7fffu + ((u >> 16) & 1u)) >> 16;
  return (short)r;
}

DEVINL int packbf(float a, float b) {
  return (int)((uint32_t)(uint16_t)f2bf(a) | ((uint32_t)(uint16_t)f2bf(b) << 16));
}

// global(16B/lane) -> LDS DMA; dest = wave-uniform base + lane*16 (linear).
DEVINL void async16(const void* g, void* l) {
  __builtin_amdgcn_global_load_lds(
      (const __attribute__((address_space(1))) void*)g,
      (__attribute__((address_space(3))) void*)l, 16, 0, 0);
}

// swizzled LDS short-index for [row][kg8] tiles (128B row pitch)
DEVINL int ab_off(int row, int kg) {
  return ((row * 128 + kg * 16) ^ ((row & 7) << 4)) >> 1;
}
// swizzled LDS short-index for K tile [key32][dg32] (512B row pitch)
DEVINL int k_off(int key, int dg) {
  return ((key * 512 + dg * 16) ^ ((key & 7) << 4)) >> 1;
}

// ------ fused prep: weights->bf16 | x transpose | g_vec  (one launch) --------
__global__ __launch_bounds__(256) void prep_kernel(
    const float* __restrict__ x,
    const float* __restrict__ qw1, const float* __restrict__ qw2,
    const float* __restrict__ kw1, const float* __restrict__ kw2,
    const float* __restrict__ vw, const float* __restrict__ ow,
    short* __restrict__ wbuf, short* __restrict__ xt, float* __restrict__ g) {
  __shared__ float t[32][33];
  int gblk = blockIdx.x, tid = threadIdx.x;
  if (gblk < 2560) {
    int idx = gblk * 256 + tid;
    const float* src; int base, stride, coloff, sh, mask;
    if (idx < 131072)      { src = qw1; base = 0;      stride = 512;  coloff = 0;   sh = 9; mask = 511; }
    else if (idx < 196608) { src = qw2; base = 131072; stride = 256;  coloff = 0;   sh = 8; mask = 255; }
    else if (idx < 327680) { src = kw1; base = 196608; stride = 1024; coloff = 512; sh = 9; mask = 511; }
    else if (idx < 393216) { src = kw2; base = 327680; stride = 256;  coloff = 0;   sh = 8; mask = 255; }
    else if (idx < 524288) { src = vw;  base = 393216; stride = 1024; coloff = 512; sh = 9; mask = 511; }
    else                   { src = ow;  base = 524288; stride = 256;  coloff = 0;   sh = 8; mask = 255; }
    int l = idx - base;
    int r = l >> sh, c = l & mask;
    wbuf[idx] = f2bf(src[(size_t)r * stride + coloff + c]);
  } else if (gblk < 6656) {
    int g2 = gblk - 2560;
    int nt = g2 & 127, ct = (g2 >> 7) & 15, b = g2 >> 11;
    int tx = tid & 31, ty = tid >> 5;
    for (int i = 0; i < 4; ++i) {
      int c = ct * 32 + ty + i * 8;
      t[ty + i * 8][tx] = x[((size_t)(b * 512 + c)) * 4096 + nt * 32 + tx];
    }
    __syncthreads();
    for (int i = 0; i < 4; ++i) {
      int n = nt * 32 + ty + i * 8;
      xt[((size_t)(b * 4096 + n)) * 512 + ct * 32 + tx] = f2bf(t[tx][ty + i * 8]);
    }
  } else {
    int g3 = gblk - 6656;
    int c = g3 & 511, b = g3 >> 9;
    const float* row = x + ((size_t)(b * 512 + c)) * 4096;
    int w = tid >> 6, lane = tid & 63;
    float vals[16];
    float vmax = -3e38f;
    for (int i = 0; i < 4; ++i) {
      float4 v = ((const float4*)row)[tid + i * 256];
      vals[i * 4 + 0] = v.x; vals[i * 4 + 1] = v.y;
      vals[i * 4 + 2] = v.z; vals[i * 4 + 3] = v.w;
    }
    for (int i = 0; i < 16; ++i) vmax = fmaxf(vmax, vals[i]);
    for (int off = 1; off < 64; off <<= 1) vmax = fmaxf(vmax, __shfl_xor(vmax, off));
    float* sb = &t[0][0];
    if (lane == 0) sb[w] = vmax;
    __syncthreads();
    vmax = fmaxf(fmaxf(sb[0], sb[1]), fmaxf(sb[2], sb[3]));
    float se = 0.f, sex = 0.f;
    for (int i = 0; i < 16; ++i) {
      float e = __expf(vals[i] - vmax);
      se += e; sex += e * vals[i];
    }
    for (int off = 1; off < 64; off <<= 1) {
      se += __shfl_xor(se, off);
      sex += __shfl_xor(sex, off);
    }
    __syncthreads();
    if (lane == 0) { sb[4 + w] = se; sb[8 + w] = sex; }
    __syncthreads();
    if (tid == 0) {
      float tse = sb[4] + sb[5] + sb[6] + sb[7];
      float tsx = sb[8] + sb[9] + sb[10] + sb[11];
      g[b * 512 + c] = tsx / (tse * 4096.0f);
    }
  }
}

// ------------- kbias/vbias: first-half-weight @ g_vec ------------------------
__global__ __launch_bounds__(64) void bias_kernel(const float* __restrict__ kw1,
                                                  const float* __restrict__ vw,
                                                  const float* __restrict__ g,
                                                  float* __restrict__ kbias,
                                                  float* __restrict__ vbias) {
  int o = blockIdx.x, b = blockIdx.y, which = blockIdx.z;
  const float* W = which ? vw : kw1;
  int lane = threadIdx.x;
  float s = 0.f;
  for (int j = 0; j < 8; ++j) {
    int c = lane + j * 64;
    s += W[(size_t)o * 1024 + c] * g[b * 512 + c];
  }
  for (int off = 1; off < 64; off <<= 1) s += __shfl_xor(s, off);
  if (lane == 0) (which ? vbias : kbias)[b * 256 + o] = s;
}

// -------- shared NT GEMM core: 128x64 tile, global_load_lds staging ----------
DEVINL void gemm_core(const short* __restrict__ Ap, const short* __restrict__ Bp,
                      int K, short* Alds, short* Blds, int tid,
                      f32x4 (&acc)[4][2]) {
  int lane = tid & 63, w = tid >> 6, lg = lane >> 4, ln = lane & 15;
  int wm = w & 1, wn = w >> 1;
  int nk = K >> 6;
  for (int kt = 0; kt < nk; ++kt) {
    int k0 = kt * 64;
#pragma unroll
    for (int j = 0; j < 4; ++j) {   // A tile: 1024 chunks
      int c = tid + j * 256;
      int row = c >> 3, e = c & 7;
      async16(Ap + (size_t)row * K + k0 + ((e ^ (row & 7)) * 8),
              Alds + (size_t)(c & ~63) * 8);
    }
#pragma unroll
    for (int j = 0; j < 2; ++j) {   // B tile: 512 chunks
      int c = tid + j * 256;
      int row = c >> 3, e = c & 7;
      async16(Bp + (size_t)row * K + k0 + ((e ^ (row & 7)) * 8),
              Blds + (size_t)(c & ~63) * 8);
    }
    __syncthreads();
#pragma unroll
    for (int ks = 0; ks < 2; ++ks) {
      s16x8 af[4], bfr[2];
#pragma unroll
      for (int mi = 0; mi < 4; ++mi)
        af[mi] = *(const s16x8*)(Alds + ab_off(wm * 64 + mi * 16 + ln, ks * 4 + lg));
#pragma unroll
      for (int nj = 0; nj < 2; ++nj)
        bfr[nj] = *(const s16x8*)(Blds + ab_off(wn * 32 + nj * 16 + ln, ks * 4 + lg));
#pragma unroll
      for (int mi = 0; mi < 4; ++mi)
#pragma unroll
        for (int nj = 0; nj < 2; ++nj)
          acc[mi][nj] = MFMA16(af[mi], bfr[nj], acc[mi][nj]);
    }
    __syncthreads();
  }
}

// ---------------- fused layer-1: Q1 / K1 / V  (M=256, K=512) -----------------
__global__ __launch_bounds__(256) void gemm_l1(
    const short* __restrict__ xt,
    const short* __restrict__ WQ1, const short* __restrict__ WK1,
    const short* __restrict__ WV,
    const float* __restrict__ qg1, const float* __restrict__ qb1,
    const float* __restrict__ kg1, const float* __restrict__ kb1,
    const float* __restrict__ vg, const float* __restrict__ vb,
    const float* __restrict__ kbias, const float* __restrict__ vbias,
    short* __restrict__ t1, short* __restrict__ ctxS, short* __restrict__ vbuf) {
  __shared__ alignas(16) short Alds[8192];
  __shared__ alignas(16) short Blds[4096];
  int nt = blockIdx.x, mt = blockIdx.y;
  int gid = blockIdx.z >> 1, b = blockIdx.z & 1;
  const short* A; const float *gm, *bd, *cb; short* out; bool nmode;
  if (gid == 0)      { A = WQ1; gm = qg1; bd = qb1; cb = nullptr; out = t1;   nmode = true; }
  else if (gid == 1) { A = WK1; gm = kg1; bd = kb1; cb = kbias;   out = ctxS; nmode = true; }
  else               { A = WV;  gm = vg;  bd = vb;  cb = vbias;   out = vbuf; nmode = false; }
  int tid = threadIdx.x, lane = tid & 63, w = tid >> 6, lg = lane >> 4, ln = lane & 15;
  int wm = w & 1, wn = w >> 1;
  f32x4 z = {0.f, 0.f, 0.f, 0.f};
  f32x4 acc[4][2];
  for (int mi = 0; mi < 4; ++mi) for (int nj = 0; nj < 2; ++nj) acc[mi][nj] = z;
  gemm_core(A + (size_t)(mt * 128) * 512, xt + ((size_t)b * 4096 + nt * 64) * 512,
            512, Alds, Blds, tid, acc);
  for (int mi = 0; mi < 4; ++mi)
    for (int nj = 0; nj < 2; ++nj) {
      int mbase = mt * 128 + wm * 64 + mi * 16 + lg * 4;
      int n = nt * 64 + wn * 32 + nj * 16 + ln;
      if (nmode) {
        s16x4 pack;
        for (int r = 0; r < 4; ++r) {
          float a = acc[mi][nj][r];
          if (cb) a += cb[b * 256 + mbase + r];
          pack[r] = f2bf(fmaxf(a * gm[mbase + r] + bd[mbase + r], 0.f));
        }
        *(s16x4*)(out + ((size_t)b * 4096 + n) * 256 + mbase) = pack;
      } else {
        for (int r = 0; r < 4; ++r) {
          int m = mbase + r;
          float a = acc[mi][nj][r] + cb[b * 256 + m];
          out[((size_t)(b * 256 + m)) * 4096 + n] = f2bf(fmaxf(a * gm[m] + bd[m], 0.f));
        }
      }
    }
}

// ---------------- fused layer-2: Q2 / K2  (M=256, K=256) ---------------------
__global__ __launch_bounds__(256) void gemm_l2(
    const short* __restrict__ t1, const short* __restrict__ ctxS,
    const short* __restrict__ WQ2, const short* __restrict__ WK2,
    const float* __restrict__ qg2, const float* __restrict__ qb2,
    const float* __restrict__ kg2, const float* __restrict__ kb2,
    short* __restrict__ qbuf, short* __restrict__ kbuf) {
  __shared__ alignas(16) short Alds[8192];
  __shared__ alignas(16) short Blds[4096];
  int nt = blockIdx.x, mt = blockIdx.y;
  int gid = blockIdx.z >> 1, b = blockIdx.z & 1;
  const short* A = gid ? WK2 : WQ2;
  const short* B = gid ? ctxS : t1;
  const float* gm = gid ? kg2 : qg2;
  const float* bd = gid ? kb2 : qb2;
  short* out = gid ? kbuf : qbuf;
  float scale = gid ? 1.0f : 0.0625f;
  int tid = threadIdx.x, lane = tid & 63, w = tid >> 6, lg = lane >> 4, ln = lane & 15;
  int wm = w & 1, wn = w >> 1;
  f32x4 z = {0.f, 0.f, 0.f, 0.f};
  f32x4 acc[4][2];
  for (int mi = 0; mi < 4; ++mi) for (int nj = 0; nj < 2; ++nj) acc[mi][nj] = z;
  gemm_core(A + (size_t)(mt * 128) * 256, B + ((size_t)b * 4096 + nt * 64) * 256,
            256, Alds, Blds, tid, acc);
  for (int mi = 0; mi < 4; ++mi)
    for (int nj = 0; nj < 2; ++nj) {
      int mbase = mt * 128 + wm * 64 + mi * 16 + lg * 4;
      int n = nt * 64 + wn * 32 + nj * 16 + ln;
      s16x4 pack;
      for (int r = 0; r < 4; ++r) {
        float a = acc[mi][nj][r];
        pack[r] = f2bf(fmaxf(a * gm[mbase + r] + bd[mbase + r], 0.f) * scale);
      }
      *(s16x4*)(out + ((size_t)b * 4096 + n) * 256 + mbase) = pack;
    }
}

// ---------------- final: out = relu(ctx . WO) (M=512, K=256, f32 out) --------
__global__ __launch_bounds__(256) void gemm_final(
    const short* __restrict__ ctx, const short* __restrict__ WO,
    const float* __restrict__ og, const float* __restrict__ ob,
    float* __restrict__ out) {
  __shared__ alignas(16) short Alds[8192];
  __shared__ alignas(16) short Blds[4096];
  int nt = blockIdx.x, mt = blockIdx.y, b = blockIdx.z;
  int tid = threadIdx.x, lane = tid & 63, w = tid >> 6, lg = lane >> 4, ln = lane & 15;
  int wm = w & 1, wn = w >> 1;
  f32x4 z = {0.f, 0.f, 0.f, 0.f};
  f32x4 acc[4][2];
  for (int mi = 0; mi < 4; ++mi) for (int nj = 0; nj < 2; ++nj) acc[mi][nj] = z;
  gemm_core(WO + (size_t)(mt * 128) * 256, ctx + ((size_t)b * 4096 + nt * 64) * 256,
            256, Alds, Blds, tid, acc);
  for (int mi = 0; mi < 4; ++mi)
    for (int nj = 0; nj < 2; ++nj) {
      int mbase = mt * 128 + wm * 64 + mi * 16 + lg * 4;
      int n = nt * 64 + wn * 32 + nj * 16 + ln;
      for (int r = 0; r < 4; ++r) {
        int m = mbase + r;
        float y = fmaxf(acc[mi][nj][r] * og[m] + ob[m], 0.f);
        out[((size_t)(b * 512 + m)) * 4096 + n] = y;
      }
    }
}

// ----- flash attention: QBLK=16 QK^T, d-split PV (V read once per block) -----
// q,k: (b, n, 256) bf16 (q pre-scaled by 1/16); v: (b, 256, n) bf16
// Wave w: softmax owner of q-rows w*16+ln; PV owner of d-slice [w*64,w*64+64)
// for ALL 64 block q-rows (V-frags de-replicated; P read cross-wave).
__global__ __launch_bounds__(256, 2) void attn_kernel(
    const short* __restrict__ q, const short* __restrict__ k,
    const short* __restrict__ v, float* __restrict__ accp,
    float* __restrict__ mlp, int nsplit) {
  __shared__ alignas(16) short Klds[2][8192];  // [key32][dg32][8], xor-swizzled
  __shared__ alignas(16) short Vlds[2][8192];  // [kg4][d256][8], unit^=(kg&1)<<2
  __shared__ alignas(16) short Plds[4][512];   // per-wave [q16][8 units]
  __shared__ float alds[4][16];                // per-tile rescale alphas
  __shared__ int gflag[4];
  int qt = blockIdx.x, split = blockIdx.y, b = blockIdx.z;
  int tid = threadIdx.x, w = tid >> 6, lane = tid & 63, lg = lane >> 4, ln = lane & 15;

  const short* qrow = q + ((size_t)(b * 4096) + qt * 64 + w * 16 + ln) * 256;
  s16x8 qf[8];
#pragma unroll
  for (int kc = 0; kc < 8; ++kc) qf[kc] = *(const s16x8*)(qrow + kc * 32 + lg * 8);

  f32x4 z = {0.f, 0.f, 0.f, 0.f};
  f32x4 acc4[4][4];  // [qg][dfl]: rows qg*16+lg*4+r, cols w*64+dfl*16+ln
#pragma unroll
  for (int i = 0; i < 4; ++i)
#pragma unroll
    for (int j = 0; j < 4; ++j) acc4[i][j] = z;
  float m_run = -3e38f, l_run = 0.f;

  const size_t kvbase = (size_t)b * 4096 * 256;
  const short* kb_ = k + kvbase;
  const short* vb_ = v + kvbase;
  int kps = 4096 / nsplit;
  int ntiles = kps >> 5;
  int* pw = (int*)&Plds[w][0];

  // T14 staging registers (prologue load for tile 0)
  s16x8 kst[4], vst[4];
  {
    int key0 = split * kps;
#pragma unroll
    for (int j = 0; j < 4; ++j) {
      int c = tid + j * 256;
      kst[j] = *(const s16x8*)(kb_ + (size_t)(key0 + (c >> 5)) * 256 + (c & 31) * 8);
      vst[j] = *(const s16x8*)(vb_ + (size_t)(c >> 2) * 4096 + key0 + (c & 3) * 8);
    }
  }

  int cur = 0;
  for (int tile = 0; tile < ntiles; ++tile) {
    // write staged regs -> LDS buffer[cur]
    short* Kc = &Klds[cur][0];
    short* Vc = &Vlds[cur][0];
#pragma unroll
    for (int j = 0; j < 4; ++j) {
      int c = tid + j * 256;
      *(s16x8*)(Kc + k_off(c >> 5, c & 31)) = kst[j];
      int d = c >> 2, kg = c & 3;
      *(s16x8*)(Vc + (((kg * 256 + d) ^ ((kg & 1) << 2)) * 8)) = vst[j];
    }
    __syncthreads();  // A: staging visible (also gates prev-tile P/acc use)
    // issue next tile's global loads NOW — latency hides under compute below
    if (tile + 1 < ntiles) {
      int nk0 = split * kps + (tile + 1) * 32;
#pragma unroll
      for (int j = 0; j < 4; ++j) {
        int c = tid + j * 256;
        kst[j] = *(const s16x8*)(kb_ + (size_t)(nk0 + (c >> 5)) * 256 + (c & 31) * 8);
        vst[j] = *(const s16x8*)(vb_ + (size_t)(c >> 2) * 4096 + nk0 + (c & 3) * 8);
      }
    }
    // S^T = K . Q^T  (lane holds S[keys lg*4+r (+16)][q-row ln])
    f32x4 sf0 = z, sf1 = z;
    __builtin_amdgcn_s_setprio(1);
#pragma unroll
    for (int kc = 0; kc < 8; ++kc) {
      s16x8 kb0 = *(const s16x8*)(Kc + k_off(ln, kc * 4 + lg));
      s16x8 kb1 = *(const s16x8*)(Kc + k_off(16 + ln, kc * 4 + lg));
      sf0 = MFMA16(kb0, qf[kc], sf0);
      sf1 = MFMA16(kb1, qf[kc], sf1);
    }
    __builtin_amdgcn_s_setprio(0);
    // row (q=ln) softmax: local max of 8 + 2 cross-quarter shuffles
    float mx = fmaxf(fmaxf(fmaxf(sf0[0], sf0[1]), fmaxf(sf0[2], sf0[3])),
                     fmaxf(fmaxf(sf1[0], sf1[1]), fmaxf(sf1[2], sf1[3])));
    mx = fmaxf(mx, __shfl_xor(mx, 16));
    mx = fmaxf(mx, __shfl_xor(mx, 32));
    float alpha = 1.0f; int grew = 0;
    if (__any(mx > m_run + 8.0f)) {   // defer-max (THR=8)
      float mnew = fmaxf(m_run, mx);
      alpha = __expf(m_run - mnew);
      m_run = mnew;
      l_run *= alpha;
      grew = 1;
    }
    if (lane < 16) alds[w][ln] = alpha;
    if (lane == 0) gflag[w] = grew;
    float p0[4], p1[4];
    float ps = 0.f;
#pragma unroll
    for (int r = 0; r < 4; ++r) {
      p0[r] = __expf(sf0[r] - m_run);
      p1[r] = __expf(sf1[r] - m_run);
      ps += p0[r] + p1[r];
    }
    ps += __shfl_xor(ps, 16);
    ps += __shfl_xor(ps, 32);
    l_run += ps;
    // P -> LDS transpose: row ln, 8B unit u (keys 4u..4u+3), swizzle u^=ln&7
    int u0 = lg ^ (ln & 7);
    int u1 = (4 | lg) ^ (ln & 7);
    *(int2*)(pw + ln * 16 + u0 * 2) = make_int2(packbf(p0[0], p0[1]), packbf(p0[2], p0[3]));
    *(int2*)(pw + ln * 16 + u1 * 2) = make_int2(packbf(p1[0], p1[1]), packbf(p1[2], p1[3]));
    __syncthreads();  // B: all waves' P + alphas visible
    // rescale own acc slice with per-row alphas (rare; block-uniform branch)
    if (gflag[0] | gflag[1] | gflag[2] | gflag[3]) {
#pragma unroll
      for (int qg = 0; qg < 4; ++qg) {
        float a0 = alds[qg][lg * 4 + 0];
        float a1 = alds[qg][lg * 4 + 1];
        float a2 = alds[qg][lg * 4 + 2];
        float a3 = alds[qg][lg * 4 + 3];
#pragma unroll
        for (int dfl = 0; dfl < 4; ++dfl) {
          acc4[qg][dfl][0] *= a0; acc4[qg][dfl][1] *= a1;
          acc4[qg][dfl][2] *= a2; acc4[qg][dfl][3] *= a3;
        }
      }
    }
    // read all 4 waves' P A-fragments (row ln, keys lg*8..lg*8+7)
    s16x8 paw[4];
#pragma unroll
    for (int qg = 0; qg < 4; ++qg) {
      int* pq = (int*)&Plds[qg][0];
      int2 a0 = *(int2*)(pq + ln * 16 + (((2 * lg) ^ (ln & 7)) * 2));
      int2 a1 = *(int2*)(pq + ln * 16 + (((2 * lg + 1) ^ (ln & 7)) * 2));
      i32x4 pt; pt.x = a0.x; pt.y = a0.y; pt.z = a1.x; pt.w = a1.y;
      paw[qg] = __builtin_bit_cast(s16x8, pt);
    }
    // PV: wave w covers d-slice [w*64, w*64+64) for all 64 q-rows
    __builtin_amdgcn_s_setprio(1);
#pragma unroll
    for (int dfl = 0; dfl < 4; ++dfl) {
      int df = (w << 2) + dfl;
      int unit = (lg * 256 + df * 16 + ln) ^ ((lg & 1) << 2);
      s16x8 vb = *(const s16x8*)(Vc + unit * 8);
      acc4[0][dfl] = MFMA16(paw[0], vb, acc4[0][dfl]);
      acc4[1][dfl] = MFMA16(paw[1], vb, acc4[1][dfl]);
      acc4[2][dfl] = MFMA16(paw[2], vb, acc4[2][dfl]);
      acc4[3][dfl] = MFMA16(paw[3], vb, acc4[3][dfl]);
    }
    __builtin_amdgcn_s_setprio(0);
    cur ^= 1;
  }
  // write out: wave w writes d-slice [w*64, w*64+64) for all 64 q-rows
  float* accbase = accp + (((size_t)(split * 2 + b) * 4096) + qt * 64) * 256 + w * 64;
#pragma unroll
  for (int qg = 0; qg < 4; ++qg)
#pragma unroll
    for (int dfl = 0; dfl < 4; ++dfl)
#pragma unroll
      for (int r = 0; r < 4; ++r)
        accbase[(size_t)(qg * 16 + lg * 4 + r) * 256 + dfl * 16 + ln] = acc4[qg][dfl][r];
  if (lane < 16) {
    size_t rowi = ((size_t)(split * 2 + b) * 4096) + qt * 64 + w * 16 + ln;
    mlp[rowi * 2] = m_run;
    mlp[rowi * 2 + 1] = l_run;
  }
}

// -------- merge KV-split partials (vectorized), normalize, -> ctx bf16 -------
__global__ __launch_bounds__(256) void attn_merge(const float* __restrict__ accp,
                                                  const float* __restrict__ mlp,
                                                  short* __restrict__ ctx, int nsplit) {
  int tid = threadIdx.x;
  int row = blockIdx.x * 4 + (tid >> 6), b = blockIdx.y;
  int lane = tid & 63;
  float M = -3e38f;
  for (int i = 0; i < nsplit; ++i)
    M = fmaxf(M, mlp[((size_t)(i * 2 + b) * 4096 + row) * 2]);
  float denom = 0.f;
  float vx = 0.f, vy = 0.f, vz = 0.f, vw = 0.f;
  for (int i = 0; i < nsplit; ++i) {
    size_t ri = (size_t)(i * 2 + b) * 4096 + row;
    float wgt = __expf(mlp[ri * 2] - M);
    denom += wgt * mlp[ri * 2 + 1];
    float4 a = *(const float4*)(accp + ri * 256 + lane * 4);
    vx += wgt * a.x; vy += wgt * a.y; vz += wgt * a.z; vw += wgt * a.w;
  }
  float inv = 1.0f / denom;
  s16x4 pack;
  pack[0] = f2bf(vx * inv); pack[1] = f2bf(vy * inv);
  pack[2] = f2bf(vz * inv); pack[3] = f2bf(vw * inv);
  *(s16x4*)(ctx + ((size_t)b * 4096 + row) * 256 + lane * 4) = pack;
}

// -----------------------------------------------------------------------------
extern "C" void kernel_launch(void* const* d_in, const int* in_sizes, int n_in,
                              void* d_out, int out_size, void* d_ws, size_t ws_size,
                              hipStream_t stream) {
  const float* x    = (const float*)d_in[0];
  const float* qw1  = (const float*)d_in[1];
  const float* qg1  = (const float*)d_in[2];
  const float* qb1  = (const float*)d_in[3];
  const float* qw2  = (const float*)d_in[4];
  const float* qg2  = (const float*)d_in[5];
  const float* qb2  = (const float*)d_in[6];
  const float* kw1  = (const float*)d_in[7];
  const float* kg1  = (const float*)d_in[8];
  const float* kb1f = (const float*)d_in[9];
  const float* kw2  = (const float*)d_in[10];
  const float* kg2  = (const float*)d_in[11];
  const float* kb2f = (const float*)d_in[12];
  const float* vw   = (const float*)d_in[13];
  const float* vg   = (const float*)d_in[14];
  const float* vbf_ = (const float*)d_in[15];
  const float* ow   = (const float*)d_in[16];
  const float* og   = (const float*)d_in[17];
  const float* ob   = (const float*)d_in[18];
  (void)in_sizes; (void)n_in;

  char* ws = (char*)d_ws;
  size_t off = 0;
  short* wbuf = (short*)(ws + off); off += 1310720;
  short* xt   = (short*)(ws + off); off += 8388608;
  float* gvec = (float*)(ws + off); off += 4096;
  float* kbias= (float*)(ws + off); off += 4096;
  float* vbias= (float*)(ws + off); off += 4096;
  short* t1   = (short*)(ws + off); off += 4194304;
  short* qbuf = (short*)(ws + off); off += 4194304;
  short* kbuf = (short*)(ws + off); off += 4194304;
  short* vbuf = (short*)(ws + off); off += 4194304;
  short* ctx  = (short*)(ws + off); off += 4194304;
  float* mlp  = (float*)(ws + off); off += 524288;
  float* accp = (float*)(ws + off);
  size_t basesz = off;
  const size_t per = 8388608ull;  // accp bytes per split
  int nsplit = 1;
  if (ws_size >= basesz + 4 * per) nsplit = 4;
  else if (ws_size >= basesz + 2 * per) nsplit = 2;
  else if (ws_size < basesz + per)
    accp = (float*)d_out;  // safe: consumed by attn_merge before final GEMM

  prep_kernel<<<7680, 256, 0, stream>>>(x, qw1, qw2, kw1, kw2, vw, ow,
                                        wbuf, xt, gvec);
  bias_kernel<<<dim3(256, 2, 2), 64, 0, stream>>>(kw1, vw, gvec, kbias, vbias);

  short* WQ1 = wbuf + 0;
  short* WQ2 = wbuf + 131072;
  short* WK1 = wbuf + 196608;
  short* WK2 = wbuf + 327680;
  short* WV  = wbuf + 393216;
  short* WO  = wbuf + 524288;

  gemm_l1<<<dim3(64, 2, 6), 256, 0, stream>>>(xt, WQ1, WK1, WV,
                                              qg1, qb1, kg1, kb1f, vg, vbf_,
                                              kbias, vbias, t1, ctx, vbuf);
  gemm_l2<<<dim3(64, 2, 4), 256, 0, stream>>>(t1, ctx, WQ2, WK2,
                                              qg2, qb2, kg2, kb2f, qbuf, kbuf);

  attn_kernel<<<dim3(64, nsplit, 2), 256, 0, stream>>>(qbuf, kbuf, vbuf, accp, mlp, nsplit);
  attn_merge<<<dim3(1024, 2), 256, 0, stream>>>(accp, mlp, ctx, nsplit);

  gemm_final<<<dim3(64, 4, 2), 256, 0, stream>>>(ctx, WO, og, ob, (float*)d_out);
}

// Round 18
// 117.577 us; speedup vs baseline: 1.0231x; 1.0231x over previous
//
#include <hip/hip_runtime.h>
#include <stdint.h>

#define DEVINL __device__ __forceinline__

typedef short s16x8 __attribute__((ext_vector_type(8)));
typedef short s16x4 __attribute__((ext_vector_type(4)));
typedef float f32x4 __attribute__((ext_vector_type(4)));
typedef int   i32x4 __attribute__((ext_vector_type(4)));

DEVINL f32x4 MFMA16(s16x8 a, s16x8 b, f32x4 c) {
  return __builtin_amdgcn_mfma_f32_16x16x32_bf16(a, b, c, 0, 0, 0);
}

DEVINL short f2bf(float f) {
  uint32_t u = __float_as_uint(f);
  uint32_t r = (u + 0x7fffu + ((u >> 16) & 1u)) >> 16;
  return (short)r;
}

DEVINL int packbf(float a, float b) {
  return (int)((uint32_t)(uint16_t)f2bf(a) | ((uint32_t)(uint16_t)f2bf(b) << 16));
}

// global(16B/lane) -> LDS DMA; dest = wave-uniform base + lane*16 (linear).
DEVINL void async16(const void* g, void* l) {
  __builtin_amdgcn_global_load_lds(
      (const __attribute__((address_space(1))) void*)g,
      (__attribute__((address_space(3))) void*)l, 16, 0, 0);
}

// swizzled LDS short-index for [row][kg8] tiles (128B row pitch)
DEVINL int ab_off(int row, int kg) {
  return ((row * 128 + kg * 16) ^ ((row & 7) << 4)) >> 1;
}
// swizzled LDS short-index for K tile [key32][dg32] (512B row pitch)
DEVINL int k_off(int key, int dg) {
  return ((key * 512 + dg * 16) ^ ((key & 7) << 4)) >> 1;
}

// ------ fused prep: weights->bf16 | x transpose | g_vec  (one launch) --------
__global__ __launch_bounds__(256) void prep_kernel(
    const float* __restrict__ x,
    const float* __restrict__ qw1, const float* __restrict__ qw2,
    const float* __restrict__ kw1, const float* __restrict__ kw2,
    const float* __restrict__ vw, const float* __restrict__ ow,
    short* __restrict__ wbuf, short* __restrict__ xt, float* __restrict__ g) {
  __shared__ float t[32][33];
  int gblk = blockIdx.x, tid = threadIdx.x;
  if (gblk < 2560) {
    int idx = gblk * 256 + tid;
    const float* src; int base, stride, coloff, sh, mask;
    if (idx < 131072)      { src = qw1; base = 0;      stride = 512;  coloff = 0;   sh = 9; mask = 511; }
    else if (idx < 196608) { src = qw2; base = 131072; stride = 256;  coloff = 0;   sh = 8; mask = 255; }
    else if (idx < 327680) { src = kw1; base = 196608; stride = 1024; coloff = 512; sh = 9; mask = 511; }
    else if (idx < 393216) { src = kw2; base = 327680; stride = 256;  coloff = 0;   sh = 8; mask = 255; }
    else if (idx < 524288) { src = vw;  base = 393216; stride = 1024; coloff = 512; sh = 9; mask = 511; }
    else                   { src = ow;  base = 524288; stride = 256;  coloff = 0;   sh = 8; mask = 255; }
    int l = idx - base;
    int r = l >> sh, c = l & mask;
    wbuf[idx] = f2bf(src[(size_t)r * stride + coloff + c]);
  } else if (gblk < 6656) {
    int g2 = gblk - 2560;
    int nt = g2 & 127, ct = (g2 >> 7) & 15, b = g2 >> 11;
    int tx = tid & 31, ty = tid >> 5;
    for (int i = 0; i < 4; ++i) {
      int c = ct * 32 + ty + i * 8;
      t[ty + i * 8][tx] = x[((size_t)(b * 512 + c)) * 4096 + nt * 32 + tx];
    }
    __syncthreads();
    for (int i = 0; i < 4; ++i) {
      int n = nt * 32 + ty + i * 8;
      xt[((size_t)(b * 4096 + n)) * 512 + ct * 32 + tx] = f2bf(t[tx][ty + i * 8]);
    }
  } else {
    int g3 = gblk - 6656;
    int c = g3 & 511, b = g3 >> 9;
    const float* row = x + ((size_t)(b * 512 + c)) * 4096;
    int w = tid >> 6, lane = tid & 63;
    float vals[16];
    float vmax = -3e38f;
    for (int i = 0; i < 4; ++i) {
      float4 v = ((const float4*)row)[tid + i * 256];
      vals[i * 4 + 0] = v.x; vals[i * 4 + 1] = v.y;
      vals[i * 4 + 2] = v.z; vals[i * 4 + 3] = v.w;
    }
    for (int i = 0; i < 16; ++i) vmax = fmaxf(vmax, vals[i]);
    for (int off = 1; off < 64; off <<= 1) vmax = fmaxf(vmax, __shfl_xor(vmax, off));
    float* sb = &t[0][0];
    if (lane == 0) sb[w] = vmax;
    __syncthreads();
    vmax = fmaxf(fmaxf(sb[0], sb[1]), fmaxf(sb[2], sb[3]));
    float se = 0.f, sex = 0.f;
    for (int i = 0; i < 16; ++i) {
      float e = __expf(vals[i] - vmax);
      se += e; sex += e * vals[i];
    }
    for (int off = 1; off < 64; off <<= 1) {
      se += __shfl_xor(se, off);
      sex += __shfl_xor(sex, off);
    }
    __syncthreads();
    if (lane == 0) { sb[4 + w] = se; sb[8 + w] = sex; }
    __syncthreads();
    if (tid == 0) {
      float tse = sb[4] + sb[5] + sb[6] + sb[7];
      float tsx = sb[8] + sb[9] + sb[10] + sb[11];
      g[b * 512 + c] = tsx / (tse * 4096.0f);
    }
  }
}

// ------------- kbias/vbias: first-half-weight @ g_vec ------------------------
__global__ __launch_bounds__(64) void bias_kernel(const float* __restrict__ kw1,
                                                  const float* __restrict__ vw,
                                                  const float* __restrict__ g,
                                                  float* __restrict__ kbias,
                                                  float* __restrict__ vbias) {
  int o = blockIdx.x, b = blockIdx.y, which = blockIdx.z;
  const float* W = which ? vw : kw1;
  int lane = threadIdx.x;
  float s = 0.f;
  for (int j = 0; j < 8; ++j) {
    int c = lane + j * 64;
    s += W[(size_t)o * 1024 + c] * g[b * 512 + c];
  }
  for (int off = 1; off < 64; off <<= 1) s += __shfl_xor(s, off);
  if (lane == 0) (which ? vbias : kbias)[b * 256 + o] = s;
}

// -------- shared NT GEMM core: 128x64 tile, global_load_lds staging ----------
DEVINL void gemm_core(const short* __restrict__ Ap, const short* __restrict__ Bp,
                      int K, short* Alds, short* Blds, int tid,
                      f32x4 (&acc)[4][2]) {
  int lane = tid & 63, w = tid >> 6, lg = lane >> 4, ln = lane & 15;
  int wm = w & 1, wn = w >> 1;
  int nk = K >> 6;
  for (int kt = 0; kt < nk; ++kt) {
    int k0 = kt * 64;
#pragma unroll
    for (int j = 0; j < 4; ++j) {   // A tile: 1024 chunks
      int c = tid + j * 256;
      int row = c >> 3, e = c & 7;
      async16(Ap + (size_t)row * K + k0 + ((e ^ (row & 7)) * 8),
              Alds + (size_t)(c & ~63) * 8);
    }
#pragma unroll
    for (int j = 0; j < 2; ++j) {   // B tile: 512 chunks
      int c = tid + j * 256;
      int row = c >> 3, e = c & 7;
      async16(Bp + (size_t)row * K + k0 + ((e ^ (row & 7)) * 8),
              Blds + (size_t)(c & ~63) * 8);
    }
    __syncthreads();
#pragma unroll
    for (int ks = 0; ks < 2; ++ks) {
      s16x8 af[4], bfr[2];
#pragma unroll
      for (int mi = 0; mi < 4; ++mi)
        af[mi] = *(const s16x8*)(Alds + ab_off(wm * 64 + mi * 16 + ln, ks * 4 + lg));
#pragma unroll
      for (int nj = 0; nj < 2; ++nj)
        bfr[nj] = *(const s16x8*)(Blds + ab_off(wn * 32 + nj * 16 + ln, ks * 4 + lg));
#pragma unroll
      for (int mi = 0; mi < 4; ++mi)
#pragma unroll
        for (int nj = 0; nj < 2; ++nj)
          acc[mi][nj] = MFMA16(af[mi], bfr[nj], acc[mi][nj]);
    }
    __syncthreads();
  }
}

// ---------------- fused layer-1: Q1 / K1 / V  (M=256, K=512) -----------------
__global__ __launch_bounds__(256) void gemm_l1(
    const short* __restrict__ xt,
    const short* __restrict__ WQ1, const short* __restrict__ WK1,
    const short* __restrict__ WV,
    const float* __restrict__ qg1, const float* __restrict__ qb1,
    const float* __restrict__ kg1, const float* __restrict__ kb1,
    const float* __restrict__ vg, const float* __restrict__ vb,
    const float* __restrict__ kbias, const float* __restrict__ vbias,
    short* __restrict__ t1, short* __restrict__ ctxS, short* __restrict__ vbuf) {
  __shared__ alignas(16) short Alds[8192];
  __shared__ alignas(16) short Blds[4096];
  int nt = blockIdx.x, mt = blockIdx.y;
  int gid = blockIdx.z >> 1, b = blockIdx.z & 1;
  const short* A; const float *gm, *bd, *cb; short* out; bool nmode;
  if (gid == 0)      { A = WQ1; gm = qg1; bd = qb1; cb = nullptr; out = t1;   nmode = true; }
  else if (gid == 1) { A = WK1; gm = kg1; bd = kb1; cb = kbias;   out = ctxS; nmode = true; }
  else               { A = WV;  gm = vg;  bd = vb;  cb = vbias;   out = vbuf; nmode = false; }
  int tid = threadIdx.x, lane = tid & 63, w = tid >> 6, lg = lane >> 4, ln = lane & 15;
  int wm = w & 1, wn = w >> 1;
  f32x4 z = {0.f, 0.f, 0.f, 0.f};
  f32x4 acc[4][2];
  for (int mi = 0; mi < 4; ++mi) for (int nj = 0; nj < 2; ++nj) acc[mi][nj] = z;
  gemm_core(A + (size_t)(mt * 128) * 512, xt + ((size_t)b * 4096 + nt * 64) * 512,
            512, Alds, Blds, tid, acc);
  for (int mi = 0; mi < 4; ++mi)
    for (int nj = 0; nj < 2; ++nj) {
      int mbase = mt * 128 + wm * 64 + mi * 16 + lg * 4;
      int n = nt * 64 + wn * 32 + nj * 16 + ln;
      if (nmode) {
        s16x4 pack;
        for (int r = 0; r < 4; ++r) {
          float a = acc[mi][nj][r];
          if (cb) a += cb[b * 256 + mbase + r];
          pack[r] = f2bf(fmaxf(a * gm[mbase + r] + bd[mbase + r], 0.f));
        }
        *(s16x4*)(out + ((size_t)b * 4096 + n) * 256 + mbase) = pack;
      } else {
        for (int r = 0; r < 4; ++r) {
          int m = mbase + r;
          float a = acc[mi][nj][r] + cb[b * 256 + m];
          out[((size_t)(b * 256 + m)) * 4096 + n] = f2bf(fmaxf(a * gm[m] + bd[m], 0.f));
        }
      }
    }
}

// ---------------- fused layer-2: Q2 / K2  (M=256, K=256) ---------------------
__global__ __launch_bounds__(256) void gemm_l2(
    const short* __restrict__ t1, const short* __restrict__ ctxS,
    const short* __restrict__ WQ2, const short* __restrict__ WK2,
    const float* __restrict__ qg2, const float* __restrict__ qb2,
    const float* __restrict__ kg2, const float* __restrict__ kb2,
    short* __restrict__ qbuf, short* __restrict__ kbuf) {
  __shared__ alignas(16) short Alds[8192];
  __shared__ alignas(16) short Blds[4096];
  int nt = blockIdx.x, mt = blockIdx.y;
  int gid = blockIdx.z >> 1, b = blockIdx.z & 1;
  const short* A = gid ? WK2 : WQ2;
  const short* B = gid ? ctxS : t1;
  const float* gm = gid ? kg2 : qg2;
  const float* bd = gid ? kb2 : qb2;
  short* out = gid ? kbuf : qbuf;
  float scale = gid ? 1.0f : 0.0625f;
  int tid = threadIdx.x, lane = tid & 63, w = tid >> 6, lg = lane >> 4, ln = lane & 15;
  int wm = w & 1, wn = w >> 1;
  f32x4 z = {0.f, 0.f, 0.f, 0.f};
  f32x4 acc[4][2];
  for (int mi = 0; mi < 4; ++mi) for (int nj = 0; nj < 2; ++nj) acc[mi][nj] = z;
  gemm_core(A + (size_t)(mt * 128) * 256, B + ((size_t)b * 4096 + nt * 64) * 256,
            256, Alds, Blds, tid, acc);
  for (int mi = 0; mi < 4; ++mi)
    for (int nj = 0; nj < 2; ++nj) {
      int mbase = mt * 128 + wm * 64 + mi * 16 + lg * 4;
      int n = nt * 64 + wn * 32 + nj * 16 + ln;
      s16x4 pack;
      for (int r = 0; r < 4; ++r) {
        float a = acc[mi][nj][r];
        pack[r] = f2bf(fmaxf(a * gm[mbase + r] + bd[mbase + r], 0.f) * scale);
      }
      *(s16x4*)(out + ((size_t)b * 4096 + n) * 256 + mbase) = pack;
    }
}

// ---------------- final: out = relu(ctx . WO) (M=512, K=256, f32 out) --------
__global__ __launch_bounds__(256) void gemm_final(
    const short* __restrict__ ctx, const short* __restrict__ WO,
    const float* __restrict__ og, const float* __restrict__ ob,
    float* __restrict__ out) {
  __shared__ alignas(16) short Alds[8192];
  __shared__ alignas(16) short Blds[4096];
  int nt = blockIdx.x, mt = blockIdx.y, b = blockIdx.z;
  int tid = threadIdx.x, lane = tid & 63, w = tid >> 6, lg = lane >> 4, ln = lane & 15;
  int wm = w & 1, wn = w >> 1;
  f32x4 z = {0.f, 0.f, 0.f, 0.f};
  f32x4 acc[4][2];
  for (int mi = 0; mi < 4; ++mi) for (int nj = 0; nj < 2; ++nj) acc[mi][nj] = z;
  gemm_core(WO + (size_t)(mt * 128) * 256, ctx + ((size_t)b * 4096 + nt * 64) * 256,
            256, Alds, Blds, tid, acc);
  for (int mi = 0; mi < 4; ++mi)
    for (int nj = 0; nj < 2; ++nj) {
      int mbase = mt * 128 + wm * 64 + mi * 16 + lg * 4;
      int n = nt * 64 + wn * 32 + nj * 16 + ln;
      for (int r = 0; r < 4; ++r) {
        int m = mbase + r;
        float y = fmaxf(acc[mi][nj][r] * og[m] + ob[m], 0.f);
        out[((size_t)(b * 512 + m)) * 4096 + n] = y;
      }
    }
}

// ---------------- flash attention, swapped QK^T, T14 async-stage -------------
// (round-16 verified best: reg-staged, 2 barriers, QBLK=16, nsplit=4)
__global__ __launch_bounds__(256, 2) void attn_kernel(
    const short* __restrict__ q, const short* __restrict__ k,
    const short* __restrict__ v, float* __restrict__ accp,
    float* __restrict__ mlp, int nsplit) {
  __shared__ alignas(16) short Klds[8192];   // [key32][dg32][8], xor-swizzled
  __shared__ alignas(16) short Vlds[8192];   // [kg4][d256][8], unit^=(kg&1)<<2
  __shared__ alignas(16) short Plds[4][512]; // per-wave [q16][8 units], unit^=ln&7
  int qt = blockIdx.x, split = blockIdx.y, b = blockIdx.z;
  int tid = threadIdx.x, w = tid >> 6, lane = tid & 63, lg = lane >> 4, ln = lane & 15;

  const short* qrow = q + ((size_t)(b * 4096) + qt * 64 + w * 16 + ln) * 256;
  s16x8 qf[8];
#pragma unroll
  for (int kc = 0; kc < 8; ++kc) qf[kc] = *(const s16x8*)(qrow + kc * 32 + lg * 8);

  f32x4 z = {0.f, 0.f, 0.f, 0.f};
  f32x4 acc[16];
#pragma unroll
  for (int i = 0; i < 16; ++i) acc[i] = z;
  float m_run = -3e38f, l_run = 0.f;

  const size_t kvbase = (size_t)b * 4096 * 256;
  const short* kb_ = k + kvbase;
  const short* vb_ = v + kvbase;
  int kps = 4096 / nsplit;
  int ntiles = kps >> 5;
  int* pw = (int*)&Plds[w][0];

  // T14 staging registers (prologue load for tile 0)
  s16x8 kst[4], vst[4];
  {
    int key0 = split * kps;
#pragma unroll
    for (int j = 0; j < 4; ++j) {
      int c = tid + j * 256;
      kst[j] = *(const s16x8*)(kb_ + (size_t)(key0 + (c >> 5)) * 256 + (c & 31) * 8);
      vst[j] = *(const s16x8*)(vb_ + (size_t)(c >> 2) * 4096 + key0 + (c & 3) * 8);
    }
  }

  for (int tile = 0; tile < ntiles; ++tile) {
    // write staged regs -> LDS (waits vmcnt on the staged loads implicitly)
#pragma unroll
    for (int j = 0; j < 4; ++j) {
      int c = tid + j * 256;
      *(s16x8*)(Klds + k_off(c >> 5, c & 31)) = kst[j];
      int d = c >> 2, kg = c & 3;
      *(s16x8*)(Vlds + (((kg * 256 + d) ^ ((kg & 1) << 2)) * 8)) = vst[j];
    }
    __syncthreads();
    // issue next tile's global loads NOW — latency hides under compute below
    if (tile + 1 < ntiles) {
      int nk0 = split * kps + (tile + 1) * 32;
#pragma unroll
      for (int j = 0; j < 4; ++j) {
        int c = tid + j * 256;
        kst[j] = *(const s16x8*)(kb_ + (size_t)(nk0 + (c >> 5)) * 256 + (c & 31) * 8);
        vst[j] = *(const s16x8*)(vb_ + (size_t)(c >> 2) * 4096 + nk0 + (c & 3) * 8);
      }
    }
    // S^T = K . Q^T  (lane holds S[keys lg*4+r (+16)][q-row ln])
    f32x4 sf0 = z, sf1 = z;
    __builtin_amdgcn_s_setprio(1);
#pragma unroll
    for (int kc = 0; kc < 8; ++kc) {
      s16x8 kb0 = *(const s16x8*)(Klds + k_off(ln, kc * 4 + lg));
      s16x8 kb1 = *(const s16x8*)(Klds + k_off(16 + ln, kc * 4 + lg));
      sf0 = MFMA16(kb0, qf[kc], sf0);
      sf1 = MFMA16(kb1, qf[kc], sf1);
    }
    __builtin_amdgcn_s_setprio(0);
    // row (q=ln) softmax: local max of 8 + 2 cross-quarter shuffles
    float mx = fmaxf(fmaxf(fmaxf(sf0[0], sf0[1]), fmaxf(sf0[2], sf0[3])),
                     fmaxf(fmaxf(sf1[0], sf1[1]), fmaxf(sf1[2], sf1[3])));
    mx = fmaxf(mx, __shfl_xor(mx, 16));
    mx = fmaxf(mx, __shfl_xor(mx, 32));
    if (__any(mx > m_run + 8.0f)) {   // defer-max (THR=8)
      float mnew = fmaxf(m_run, mx);
      float alpha = __expf(m_run - mnew);
      m_run = mnew;
      l_run *= alpha;
      float ar0 = __shfl(alpha, lg * 4 + 0);
      float ar1 = __shfl(alpha, lg * 4 + 1);
      float ar2 = __shfl(alpha, lg * 4 + 2);
      float ar3 = __shfl(alpha, lg * 4 + 3);
#pragma unroll
      for (int df = 0; df < 16; ++df) {
        acc[df][0] *= ar0; acc[df][1] *= ar1;
        acc[df][2] *= ar2; acc[df][3] *= ar3;
      }
    }
    float p0[4], p1[4];
    float ps = 0.f;
#pragma unroll
    for (int r = 0; r < 4; ++r) {
      p0[r] = __expf(sf0[r] - m_run);
      p1[r] = __expf(sf1[r] - m_run);
      ps += p0[r] + p1[r];
    }
    ps += __shfl_xor(ps, 16);
    ps += __shfl_xor(ps, 32);
    l_run += ps;
    // P -> LDS transpose: row ln, 8B unit u (keys 4u..4u+3), swizzle u^=ln&7
    int u0 = lg ^ (ln & 7);
    int u1 = (4 | lg) ^ (ln & 7);
    *(int2*)(pw + ln * 16 + u0 * 2) = make_int2(packbf(p0[0], p0[1]), packbf(p0[2], p0[3]));
    *(int2*)(pw + ln * 16 + u1 * 2) = make_int2(packbf(p1[0], p1[1]), packbf(p1[2], p1[3]));
    // read back this lane's PV A-fragment: row ln, keys lg*8..lg*8+7
    int2 a0 = *(int2*)(pw + ln * 16 + (((2 * lg) ^ (ln & 7)) * 2));
    int2 a1 = *(int2*)(pw + ln * 16 + (((2 * lg + 1) ^ (ln & 7)) * 2));
    i32x4 pt; pt.x = a0.x; pt.y = a0.y; pt.z = a1.x; pt.w = a1.y;
    s16x8 pa = __builtin_bit_cast(s16x8, pt);
    // PV
    __builtin_amdgcn_s_setprio(1);
#pragma unroll
    for (int df = 0; df < 16; ++df) {
      int unit = (lg * 256 + df * 16 + ln) ^ ((lg & 1) << 2);
      s16x8 vb = *(const s16x8*)(Vlds + unit * 8);
      acc[df] = MFMA16(pa, vb, acc[df]);
    }
    __builtin_amdgcn_s_setprio(0);
    __syncthreads();
  }
  float* accrow = accp + (((size_t)(split * 2 + b) * 4096) + qt * 64 + w * 16) * 256;
#pragma unroll
  for (int df = 0; df < 16; ++df)
#pragma unroll
    for (int r = 0; r < 4; ++r)
      accrow[(size_t)(lg * 4 + r) * 256 + df * 16 + ln] = acc[df][r];
  if (lane < 16) {
    size_t rowi = ((size_t)(split * 2 + b) * 4096) + qt * 64 + w * 16 + ln;
    mlp[rowi * 2] = m_run;
    mlp[rowi * 2 + 1] = l_run;
  }
}

// -------- merge KV-split partials (vectorized), normalize, -> ctx bf16 -------
__global__ __launch_bounds__(256) void attn_merge(const float* __restrict__ accp,
                                                  const float* __restrict__ mlp,
                                                  short* __restrict__ ctx, int nsplit) {
  int tid = threadIdx.x;
  int row = blockIdx.x * 4 + (tid >> 6), b = blockIdx.y;
  int lane = tid & 63;
  float M = -3e38f;
  for (int i = 0; i < nsplit; ++i)
    M = fmaxf(M, mlp[((size_t)(i * 2 + b) * 4096 + row) * 2]);
  float denom = 0.f;
  float vx = 0.f, vy = 0.f, vz = 0.f, vw = 0.f;
  for (int i = 0; i < nsplit; ++i) {
    size_t ri = (size_t)(i * 2 + b) * 4096 + row;
    float wgt = __expf(mlp[ri * 2] - M);
    denom += wgt * mlp[ri * 2 + 1];
    float4 a = *(const float4*)(accp + ri * 256 + lane * 4);
    vx += wgt * a.x; vy += wgt * a.y; vz += wgt * a.z; vw += wgt * a.w;
  }
  float inv = 1.0f / denom;
  s16x4 pack;
  pack[0] = f2bf(vx * inv); pack[1] = f2bf(vy * inv);
  pack[2] = f2bf(vz * inv); pack[3] = f2bf(vw * inv);
  *(s16x4*)(ctx + ((size_t)b * 4096 + row) * 256 + lane * 4) = pack;
}

// -----------------------------------------------------------------------------
extern "C" void kernel_launch(void* const* d_in, const int* in_sizes, int n_in,
                              void* d_out, int out_size, void* d_ws, size_t ws_size,
                              hipStream_t stream) {
  const float* x    = (const float*)d_in[0];
  const float* qw1  = (const float*)d_in[1];
  const float* qg1  = (const float*)d_in[2];
  const float* qb1  = (const float*)d_in[3];
  const float* qw2  = (const float*)d_in[4];
  const float* qg2  = (const float*)d_in[5];
  const float* qb2  = (const float*)d_in[6];
  const float* kw1  = (const float*)d_in[7];
  const float* kg1  = (const float*)d_in[8];
  const float* kb1f = (const float*)d_in[9];
  const float* kw2  = (const float*)d_in[10];
  const float* kg2  = (const float*)d_in[11];
  const float* kb2f = (const float*)d_in[12];
  const float* vw   = (const float*)d_in[13];
  const float* vg   = (const float*)d_in[14];
  const float* vbf_ = (const float*)d_in[15];
  const float* ow   = (const float*)d_in[16];
  const float* og   = (const float*)d_in[17];
  const float* ob   = (const float*)d_in[18];
  (void)in_sizes; (void)n_in;

  char* ws = (char*)d_ws;
  size_t off = 0;
  short* wbuf = (short*)(ws + off); off += 1310720;
  short* xt   = (short*)(ws + off); off += 8388608;
  float* gvec = (float*)(ws + off); off += 4096;
  float* kbias= (float*)(ws + off); off += 4096;
  float* vbias= (float*)(ws + off); off += 4096;
  short* t1   = (short*)(ws + off); off += 4194304;
  short* qbuf = (short*)(ws + off); off += 4194304;
  short* kbuf = (short*)(ws + off); off += 4194304;
  short* vbuf = (short*)(ws + off); off += 4194304;
  short* ctx  = (short*)(ws + off); off += 4194304;
  float* mlp  = (float*)(ws + off); off += 524288;
  float* accp = (float*)(ws + off);
  size_t basesz = off;
  const size_t per = 8388608ull;  // accp bytes per split
  int nsplit = 1;
  if (ws_size >= basesz + 4 * per) nsplit = 4;
  else if (ws_size >= basesz + 2 * per) nsplit = 2;
  else if (ws_size < basesz + per)
    accp = (float*)d_out;  // safe: consumed by attn_merge before final GEMM

  prep_kernel<<<7680, 256, 0, stream>>>(x, qw1, qw2, kw1, kw2, vw, ow,
                                        wbuf, xt, gvec);
  bias_kernel<<<dim3(256, 2, 2), 64, 0, stream>>>(kw1, vw, gvec, kbias, vbias);

  short* WQ1 = wbuf + 0;
  short* WQ2 = wbuf + 131072;
  short* WK1 = wbuf + 196608;
  short* WK2 = wbuf + 327680;
  short* WV  = wbuf + 393216;
  short* WO  = wbuf + 524288;

  gemm_l1<<<dim3(64, 2, 6), 256, 0, stream>>>(xt, WQ1, WK1, WV,
                                              qg1, qb1, kg1, kb1f, vg, vbf_,
                                              kbias, vbias, t1, ctx, vbuf);
  gemm_l2<<<dim3(64, 2, 4), 256, 0, stream>>>(t1, ctx, WQ2, WK2,
                                              qg2, qb2, kg2, kb2f, qbuf, kbuf);

  attn_kernel<<<dim3(64, nsplit, 2), 256, 0, stream>>>(qbuf, kbuf, vbuf, accp, mlp, nsplit);
  attn_merge<<<dim3(1024, 2), 256, 0, stream>>>(accp, mlp, ctx, nsplit);

  gemm_final<<<dim3(64, 4, 2), 256, 0, stream>>>(ctx, WO, og, ob, (float*)d_out);
}